// Round 19
// baseline (29.566 us; speedup 1.0000x reference)
//
#include <hip/hip_runtime.h>
#include <hip/hip_bf16.h>

typedef __attribute__((ext_vector_type(8))) short short8;
typedef __attribute__((ext_vector_type(2))) float f32x2;
typedef __attribute__((ext_vector_type(4))) float f32x4;
typedef __attribute__((ext_vector_type(16))) float f32x16;

#define NROWS 65536             // BATCH * N_EDGES
#define EDGE_DIM 64
#define NODE_DIM 32
#define NN 1024                 // NODE_DIM^2

__device__ __forceinline__ short f2bf(float f) {
    unsigned u = __builtin_bit_cast(unsigned, f);
    u += 0x7FFFu + ((u >> 16) & 1u);            // round-to-nearest-even
    return (short)(u >> 16);
}

// R19 = R12 (best, 23.8 us) + two i-loop micro-fixes:
//  (1) MFMA chain split: acc_a = mfma(w1, mfma(w0, bias)) and
//      acc_b = mfma(w3, mfma(w2, 0)) are INDEPENDENT 2-chains (was one
//      4-deep dependent chain, ~80 cyc serial latency per i at only
//      2 waves/SIMD); merged in epilogue as relu(a+b)*nv (+16 adds/i,
//      cheaper than the dependency saved; chains interleave on the pipe).
//  (2) divergence-free store: after shfl_xor(32) ALL lanes hold the full
//      j-sum, so all 64 lanes store f32x2 (same bytes, no exec-mask).
// Everything else byte-identical to R12: 256 blocks x 512 threads, in-block
// W pack to 128 KB LDS, ONE barrier, 32-edge waves, single-context body,
// no launch_bounds min-occupancy arg (the R8/R13/R15 spill trap).
// Fragment layout (verified R2..R18): frag = i*4+ks;
// ldsW[(frag*64+l)*8+t] = bf16(W[ks*16 + (l>>5)*8 + t, i*32 + (l&31)]).
__global__ __launch_bounds__(512) void mp_fused(
    const float* __restrict__ node, const float* __restrict__ edge,
    const float* __restrict__ W, const float* __restrict__ bias,
    float* __restrict__ out) {
    __shared__ __align__(16) short ldsW[65536];   // 128 KB: full packed W

    const int tid = threadIdx.x;
    const int wid = tid >> 6;                 // 0..7
    const int l   = tid & 63;
    const int e32 = l & 31;                   // lane's edge col (MFMA N)
    const int h   = l >> 5;                   // lane half (k-group / row offset)
    const int eb  = blockIdx.x * 256 + wid * 32;
    const int e   = eb + e32;

    // ---- in-block W pack: wave wid packs frags [wid*16, wid*16+16) ----
#pragma unroll
    for (int m = 0; m < 16; ++m) {
        const int frag = wid * 16 + m;        // frag = i*4 + ks
        const int i  = frag >> 2;
        const int ks = frag & 3;
        const float* wp = W + (size_t)(ks * 16 + h * 8) * NN + i * 32 + e32;
        short8 v;
#pragma unroll
        for (int t = 0; t < 8; ++t)
            v[t] = f2bf(wp[(size_t)t * NN]);  // coalesced across lanes per t
        *reinterpret_cast<short8*>(&ldsW[((size_t)frag * 64 + l) * 8]) = v;
    }

    // ---- per-lane inputs (overlap the pack's VMEM stream) ----
    // ef[ks]: k = h*8+t -> edge[e, ks*16 + h*8 + t]
    // nv[q*4+rr]: acc reg r=q*4+rr -> j = q*8 + h*4 + rr
    short8 ef[4];
    float  nv[16];
    const float* erow = edge + (size_t)e * EDGE_DIM;
#pragma unroll
    for (int ks = 0; ks < 4; ++ks) {
        f32x4 a = *reinterpret_cast<const f32x4*>(erow + ks * 16 + h * 8);
        f32x4 b = *reinterpret_cast<const f32x4*>(erow + ks * 16 + h * 8 + 4);
        short8 v;
        v[0] = f2bf(a[0]); v[1] = f2bf(a[1]); v[2] = f2bf(a[2]); v[3] = f2bf(a[3]);
        v[4] = f2bf(b[0]); v[5] = f2bf(b[1]); v[6] = f2bf(b[2]); v[7] = f2bf(b[3]);
        ef[ks] = v;
    }
    const float* nrow = node + (size_t)e * NODE_DIM;
#pragma unroll
    for (int q = 0; q < 4; ++q) {
        f32x4 n = *reinterpret_cast<const f32x4*>(nrow + q * 8 + h * 4);
        nv[q * 4 + 0] = n[0]; nv[q * 4 + 1] = n[1];
        nv[q * 4 + 2] = n[2]; nv[q * 4 + 3] = n[3];
    }

    __syncthreads();                          // the ONLY barrier

    float* orow = out + (size_t)(eb + e32) * NODE_DIM;

#pragma unroll 2
    for (int iq = 0; iq < 8; ++iq) {
        f32x4 vq;
#pragma unroll
        for (int r = 0; r < 4; ++r) {
            const int i = iq * 4 + r;
            const short* wp = &ldsW[(size_t)i * 2048 + l * 8];
            short8 w0 = *reinterpret_cast<const short8*>(wp + 0 * 512);
            short8 w1 = *reinterpret_cast<const short8*>(wp + 1 * 512);
            short8 w2 = *reinterpret_cast<const short8*>(wp + 2 * 512);
            short8 w3 = *reinterpret_cast<const short8*>(wp + 3 * 512);

            // chain A: bias as C-init; chain B: zero C — independent 2-chains
            f32x16 acc_a, acc_b;
#pragma unroll
            for (int q = 0; q < 4; ++q) {
                f32x4 bq = *reinterpret_cast<const f32x4*>(bias + i * 32 + q * 8 + h * 4);
                acc_a[q * 4 + 0] = bq[0]; acc_a[q * 4 + 1] = bq[1];
                acc_a[q * 4 + 2] = bq[2]; acc_a[q * 4 + 3] = bq[3];
                acc_b[q * 4 + 0] = 0.f;   acc_b[q * 4 + 1] = 0.f;
                acc_b[q * 4 + 2] = 0.f;   acc_b[q * 4 + 3] = 0.f;
            }

            acc_a = __builtin_amdgcn_mfma_f32_32x32x16_bf16(w0, ef[0], acc_a, 0, 0, 0);
            acc_b = __builtin_amdgcn_mfma_f32_32x32x16_bf16(w2, ef[2], acc_b, 0, 0, 0);
            acc_a = __builtin_amdgcn_mfma_f32_32x32x16_bf16(w1, ef[1], acc_a, 0, 0, 0);
            acc_b = __builtin_amdgcn_mfma_f32_32x32x16_bf16(w3, ef[3], acc_b, 0, 0, 0);

            // relu(a+b) + matvec, 4 independent partials (chain depth 4)
            float s0 = 0.f, s1 = 0.f, s2 = 0.f, s3 = 0.f;
#pragma unroll
            for (int rr = 0; rr < 4; ++rr) {
                s0 += fmaxf(acc_a[rr]      + acc_b[rr],      0.f) * nv[rr];
                s1 += fmaxf(acc_a[4 + rr]  + acc_b[4 + rr],  0.f) * nv[4 + rr];
                s2 += fmaxf(acc_a[8 + rr]  + acc_b[8 + rr],  0.f) * nv[8 + rr];
                s3 += fmaxf(acc_a[12 + rr] + acc_b[12 + rr], 0.f) * nv[12 + rr];
            }
            float p = (s0 + s1) + (s2 + s3);
            p += __shfl_xor(p, 32);           // full j-sum, valid in ALL lanes
            vq[r] = p;
        }
        // divergence-free store: lane l -> row e32, cols iq*4 + h*2 .. +1
        f32x2 v2; v2[0] = vq[h * 2]; v2[1] = vq[h * 2 + 1];
        *reinterpret_cast<f32x2*>(orow + iq * 4 + h * 2) = v2;
    }
}

extern "C" void kernel_launch(void* const* d_in, const int* in_sizes, int n_in,
                              void* d_out, int out_size, void* d_ws, size_t ws_size,
                              hipStream_t stream) {
    const float* node = (const float*)d_in[0];  // [16,4096,32] f32
    const float* edge = (const float*)d_in[1];  // [16,4096,64] f32
    const float* W    = (const float*)d_in[2];  // [64,1024] f32
    const float* bias = (const float*)d_in[3];  // [1024] f32
    float* out = (float*)d_out;                 // [16,4096,32] f32

    mp_fused<<<dim3(NROWS / 256), dim3(512), 0, stream>>>(node, edge, W, bias, out);
}

// Round 20
// 23.901 us; speedup vs baseline: 1.2370x; 1.2370x over previous
//
#include <hip/hip_runtime.h>
#include <hip/hip_bf16.h>

typedef __attribute__((ext_vector_type(8))) short short8;
typedef __attribute__((ext_vector_type(4))) float f32x4;
typedef __attribute__((ext_vector_type(16))) float f32x16;

#define NROWS 65536             // BATCH * N_EDGES
#define EDGE_DIM 64
#define NODE_DIM 32
#define NN 1024                 // NODE_DIM^2

__device__ __forceinline__ short f2bf(float f) {
    unsigned u = __builtin_bit_cast(unsigned, f);
    u += 0x7FFFu + ((u >> 16) & 1u);            // round-to-nearest-even
    return (short)(u >> 16);
}

// R20 = R12 restored verbatim (measured optimum, 23.8 us). The full R12..R19
// A/B matrix shows every structural neighbor regresses:
//   +pipeline (R18): null — latency already hidden
//   64-edge waves (R14), split MFMA chains (R19): register-pressure tax
//   i-split 2 blk/CU (R15/R17): prologue+re-read tax
//   1024-thread (R13), any launch_bounds min-occ arg (R8): forced VGPR cap
//   W-in-regs (R16): strided W-load tax
// Structure: 256 blocks x 512 threads (8 waves x 32 edges). Each block packs
// full W [64,1024] f32 -> bf16 MFMA fragments into its 128 KB LDS (one-time,
// L2/L3-hot, conflict-free ds_write_b128); ONE barrier; then a barrier-free
// i-loop: 4 conflict-free ds_read_b128 + bias C-init (L1-hot) + 4-chain
// mfma_32x32x16 + relu/matvec epilogue (4 indep partials) + shfl_xor(32) +
// coalesced f32x4 stores. Fragment layout (verified R2..R19): frag = i*4+ks;
// ldsW[(frag*64+l)*8+t] = bf16(W[ks*16 + (l>>5)*8 + t, i*32 + (l&31)]).
__global__ __launch_bounds__(512) void mp_fused(
    const float* __restrict__ node, const float* __restrict__ edge,
    const float* __restrict__ W, const float* __restrict__ bias,
    float* __restrict__ out) {
    __shared__ __align__(16) short ldsW[65536];   // 128 KB: full packed W

    const int tid = threadIdx.x;
    const int wid = tid >> 6;                 // 0..7
    const int l   = tid & 63;
    const int e32 = l & 31;                   // lane's edge col (MFMA N)
    const int h   = l >> 5;                   // lane half (k-group / row offset)
    const int eb  = blockIdx.x * 256 + wid * 32;
    const int e   = eb + e32;

    // ---- in-block W pack: wave wid packs frags [wid*16, wid*16+16) ----
#pragma unroll
    for (int m = 0; m < 16; ++m) {
        const int frag = wid * 16 + m;        // frag = i*4 + ks
        const int i  = frag >> 2;
        const int ks = frag & 3;
        const float* wp = W + (size_t)(ks * 16 + h * 8) * NN + i * 32 + e32;
        short8 v;
#pragma unroll
        for (int t = 0; t < 8; ++t)
            v[t] = f2bf(wp[(size_t)t * NN]);  // coalesced across lanes per t
        *reinterpret_cast<short8*>(&ldsW[((size_t)frag * 64 + l) * 8]) = v;
    }

    // ---- per-lane inputs (overlap the pack's VMEM stream) ----
    // ef[ks]: k = h*8+t -> edge[e, ks*16 + h*8 + t]
    // nv[q*4+rr]: acc reg r=q*4+rr -> j = q*8 + h*4 + rr
    short8 ef[4];
    float  nv[16];
    const float* erow = edge + (size_t)e * EDGE_DIM;
#pragma unroll
    for (int ks = 0; ks < 4; ++ks) {
        f32x4 a = *reinterpret_cast<const f32x4*>(erow + ks * 16 + h * 8);
        f32x4 b = *reinterpret_cast<const f32x4*>(erow + ks * 16 + h * 8 + 4);
        short8 v;
        v[0] = f2bf(a[0]); v[1] = f2bf(a[1]); v[2] = f2bf(a[2]); v[3] = f2bf(a[3]);
        v[4] = f2bf(b[0]); v[5] = f2bf(b[1]); v[6] = f2bf(b[2]); v[7] = f2bf(b[3]);
        ef[ks] = v;
    }
    const float* nrow = node + (size_t)e * NODE_DIM;
#pragma unroll
    for (int q = 0; q < 4; ++q) {
        f32x4 n = *reinterpret_cast<const f32x4*>(nrow + q * 8 + h * 4);
        nv[q * 4 + 0] = n[0]; nv[q * 4 + 1] = n[1];
        nv[q * 4 + 2] = n[2]; nv[q * 4 + 3] = n[3];
    }

    __syncthreads();                          // the ONLY barrier

    float* orow = out + (size_t)(eb + (l & 31)) * NODE_DIM;

#pragma unroll 2
    for (int iq = 0; iq < 8; ++iq) {
        f32x4 vq;
#pragma unroll
        for (int r = 0; r < 4; ++r) {
            const int i = iq * 4 + r;
            const short* wp = &ldsW[(size_t)i * 2048 + l * 8];
            short8 w0 = *reinterpret_cast<const short8*>(wp + 0 * 512);
            short8 w1 = *reinterpret_cast<const short8*>(wp + 1 * 512);
            short8 w2 = *reinterpret_cast<const short8*>(wp + 2 * 512);
            short8 w3 = *reinterpret_cast<const short8*>(wp + 3 * 512);

            // bias as C-init: reg q*4+rr -> row q*8 + h*4 + rr (L1-hot)
            f32x16 acc;
#pragma unroll
            for (int q = 0; q < 4; ++q) {
                f32x4 bq = *reinterpret_cast<const f32x4*>(bias + i * 32 + q * 8 + h * 4);
                acc[q * 4 + 0] = bq[0]; acc[q * 4 + 1] = bq[1];
                acc[q * 4 + 2] = bq[2]; acc[q * 4 + 3] = bq[3];
            }

            acc = __builtin_amdgcn_mfma_f32_32x32x16_bf16(w0, ef[0], acc, 0, 0, 0);
            acc = __builtin_amdgcn_mfma_f32_32x32x16_bf16(w1, ef[1], acc, 0, 0, 0);
            acc = __builtin_amdgcn_mfma_f32_32x32x16_bf16(w2, ef[2], acc, 0, 0, 0);
            acc = __builtin_amdgcn_mfma_f32_32x32x16_bf16(w3, ef[3], acc, 0, 0, 0);

            // relu + matvec, 4 independent partials (chain depth 4)
            float s0 = 0.f, s1 = 0.f, s2 = 0.f, s3 = 0.f;
#pragma unroll
            for (int rr = 0; rr < 4; ++rr) {
                s0 += fmaxf(acc[rr],      0.f) * nv[rr];
                s1 += fmaxf(acc[4 + rr],  0.f) * nv[4 + rr];
                s2 += fmaxf(acc[8 + rr],  0.f) * nv[8 + rr];
                s3 += fmaxf(acc[12 + rr], 0.f) * nv[12 + rr];
            }
            float p = (s0 + s1) + (s2 + s3);
            p += __shfl_xor(p, 32);           // add partner half's 16 j's
            vq[r] = p;
        }
        if (l < 32)
            *reinterpret_cast<f32x4*>(orow + iq * 4) = vq;  // msg[e, iq*4..+3]
    }
}

extern "C" void kernel_launch(void* const* d_in, const int* in_sizes, int n_in,
                              void* d_out, int out_size, void* d_ws, size_t ws_size,
                              hipStream_t stream) {
    const float* node = (const float*)d_in[0];  // [16,4096,32] f32
    const float* edge = (const float*)d_in[1];  // [16,4096,64] f32
    const float* W    = (const float*)d_in[2];  // [64,1024] f32
    const float* bias = (const float*)d_in[3];  // [1024] f32
    float* out = (float*)d_out;                 // [16,4096,32] f32

    mp_fused<<<dim3(NROWS / 256), dim3(512), 0, stream>>>(node, edge, W, bias, out);
}